// Round 8
// baseline (200.179 us; speedup 1.0000x reference)
//
#include <hip/hip_runtime.h>
#include <cstdint>
#include <cstddef>

// ---------------- problem constants ----------------
#define Bb   8
#define Nn   1024
#define Ccn  768
#define Hh   12
#define DHn  64
#define Mrows (Bb * Nn)   // 8192
#define N3C  (3 * Ccn)    // 2304
#define BHn  (Bb * Hh)    // 96

typedef __attribute__((ext_vector_type(8))) short bf16x8;   // 8 bf16 (4 VGPRs)
typedef __attribute__((ext_vector_type(4))) float f32x4;

static __device__ __forceinline__ unsigned short f2bf(float f) {
    unsigned int u = __builtin_bit_cast(unsigned int, f);
    return (unsigned short)((u + 0x7FFFu + ((u >> 16) & 1u)) >> 16);  // RNE
}
static __device__ __forceinline__ float bf2f(unsigned short s) {
    unsigned int u = ((unsigned int)s) << 16;
    return __builtin_bit_cast(float, u);
}
// pack two f32 -> two bf16 (round half-up; inputs are finite non-negative p's)
static __device__ __forceinline__ unsigned pack2bf(float a, float b) {
    unsigned ua = __builtin_bit_cast(unsigned, a) + 0x8000u;
    unsigned ub = __builtin_bit_cast(unsigned, b) + 0x8000u;
    return (ua >> 16) | (ub & 0xFFFF0000u);
}
// async global->LDS, 16B per lane; LDS dest must be (wave-uniform base + lane*16)
static __device__ __forceinline__ void glds16(const void* g, void* l) {
    __builtin_amdgcn_global_load_lds((const __attribute__((address_space(1))) void*)g,
                                     (__attribute__((address_space(3))) void*)l,
                                     16, 0, 0);
}

// ---------------- merged prep kernel ----------------
// blocks [0,3072): x fp32->bf16 + mask->(0/-1e9)
// blocks [3072,5376): both weight transposes (96 x 24 tile grid flattened)
__global__ void prep_kernel(const float* __restrict__ x,
                            unsigned short* __restrict__ xb,
                            const int* __restrict__ mask,
                            float* __restrict__ maskneg,
                            const float* __restrict__ Wqkv,
                            unsigned short* __restrict__ WqkvT,
                            const float* __restrict__ Wproj,
                            unsigned short* __restrict__ WprojT) {
    __shared__ float tile[32][33];
    int bx = blockIdx.x;
    if (bx < 3072) {
        int i = bx * 256 + threadIdx.x;
        if (i < Mrows) maskneg[i] = (mask[i] != 0) ? -1.0e9f : 0.0f;
        const f32x4* xp = (const f32x4*)x;
        f32x4 a = xp[2 * i], b = xp[2 * i + 1];
        bf16x8 v;
#pragma unroll
        for (int j = 0; j < 4; ++j) {
            v[j]     = (short)f2bf(a[j]);
            v[4 + j] = (short)f2bf(b[j]);
        }
        ((bf16x8*)xb)[i] = v;
        return;
    }
    bx -= 3072;
    int xt = bx % 96, yt = bx / 96;
    const float* W; unsigned short* WT; int C;
    if (xt < 72) { W = Wqkv;  WT = WqkvT;  C = N3C; }
    else         { W = Wproj; WT = WprojT; C = Ccn; xt -= 72; }
    const int R = Ccn;
    const int c0 = xt * 32, r0 = yt * 32;
    const int tx = threadIdx.x & 31, ty = threadIdx.x >> 5;
#pragma unroll
    for (int i = 0; i < 4; ++i)
        tile[ty + i * 8][tx] = W[(size_t)(r0 + ty + i * 8) * C + c0 + tx];
    __syncthreads();
#pragma unroll
    for (int i = 0; i < 4; ++i)
        WT[(size_t)(c0 + ty + i * 8) * R + r0 + tx] = f2bf(tile[tx][ty + i * 8]);
}

// per (b,h): V (1024 x 64) bf16 -> VT (64 x 1024) bf16
__global__ void transpose_v_kernel(const unsigned short* __restrict__ vb,
                                   unsigned short* __restrict__ vtb) {
    __shared__ unsigned short tile[32][34];
    const int bh = blockIdx.z;
    const int d0 = blockIdx.x * 32, n0 = blockIdx.y * 32;
    const int tx = threadIdx.x, ty = threadIdx.y;
    const unsigned short* src = vb + (size_t)bh * Nn * DHn;
    unsigned short* dst = vtb + (size_t)bh * DHn * Nn;
#pragma unroll
    for (int i = 0; i < 4; ++i)
        tile[ty + i * 8][tx] = src[(size_t)(n0 + ty + i * 8) * DHn + d0 + tx];
    __syncthreads();
#pragma unroll
    for (int i = 0; i < 4; ++i)
        dst[(size_t)(d0 + ty + i * 8) * Nn + n0 + tx] = tile[tx][ty + i * 8];
}

// ---- bf16 GEMM, 128x128 tile, BK=32, swizzled LDS, register-free dbuf ----
__global__ __launch_bounds__(256) void gemm_qkv_kernel(
    const unsigned short* __restrict__ A,
    const unsigned short* __restrict__ BT,
    unsigned short* __restrict__ qkvb) {
    constexpr int K = Ccn;
    const int bm = blockIdx.x, bn = blockIdx.y;
    const int t = threadIdx.x, wv = t >> 6, l = t & 63;
    const int fr = l & 15, quad = l >> 4;
    const int wm = (wv >> 1) * 64, wn = (wv & 1) * 64;
    __shared__ __align__(16) unsigned short As[2][128 * 32];
    __shared__ __align__(16) unsigned short Bs[2][128 * 32];
    const f32x4 zero = {0.f, 0.f, 0.f, 0.f};
    f32x4 acc[4][4];
#pragma unroll
    for (int i = 0; i < 4; ++i)
#pragma unroll
        for (int j = 0; j < 4; ++j) acc[i][j] = zero;

    const int srow = wv * 16 + (l >> 2);                        // 0..63
    const int scol_dst = (l & 3) * 8;                           // linear dest chunk
    const int scol_src = (((l & 3) ^ ((srow >> 1) & 3)) << 3);  // swizzled source chunk
    const unsigned short* Ag = A + (size_t)(bm * 128 + srow) * K + scol_src;
    const unsigned short* Bg = BT + (size_t)(bn * 128 + srow) * K + scol_src;
    const int ldst = srow * 32 + scol_dst;
    const int rsw = ((fr >> 1) & 3);                            // read-side swizzle

    auto stage = [&](int r, int bsel) {
        const unsigned short* Ar = Ag + r * 32;
        const unsigned short* Br = Bg + r * 32;
        glds16(Ar, &As[bsel][ldst]);
        glds16(Ar + (size_t)64 * K, &As[bsel][ldst + 64 * 32]);
        glds16(Br, &Bs[bsel][ldst]);
        glds16(Br + (size_t)64 * K, &Bs[bsel][ldst + 64 * 32]);
    };
    stage(0, 0);
    __syncthreads();
    for (int r = 0; r < 24; ++r) {
        if (r < 23) stage(r + 1, (r + 1) & 1);
        const unsigned short* Asb = As[r & 1];
        const unsigned short* Bsb = Bs[r & 1];
        bf16x8 af[4], bfv[4];
#pragma unroll
        for (int i = 0; i < 4; ++i)
            af[i] = *(const bf16x8*)&Asb[(wm + i * 16 + fr) * 32 + ((quad ^ rsw) << 3)];
#pragma unroll
        for (int i = 0; i < 4; ++i)
            bfv[i] = *(const bf16x8*)&Bsb[(wn + i * 16 + fr) * 32 + ((quad ^ rsw) << 3)];
#pragma unroll
        for (int i = 0; i < 4; ++i)
#pragma unroll
            for (int j = 0; j < 4; ++j)
                acc[i][j] = __builtin_amdgcn_mfma_f32_16x16x32_bf16(af[i], bfv[j], acc[i][j], 0, 0, 0);
        __syncthreads();
    }
    // epilogue: C row = bm*128+wm+i*16+quad*4+r ; col = bn*128+wn+j*16+fr -> (s,h,d)
#pragma unroll
    for (int j = 0; j < 4; ++j) {
        int col = bn * 128 + wn + j * 16 + fr;
        int s = col / Ccn;
        int rem = col - s * Ccn;
        int hh = rem >> 6, d = rem & 63;
#pragma unroll
        for (int i = 0; i < 4; ++i) {
#pragma unroll
            for (int r = 0; r < 4; ++r) {
                int row = bm * 128 + wm + i * 16 + quad * 4 + r;
                int b = row >> 10, nq = row & 1023;
                qkvb[((((size_t)s * Bb + b) * Hh + hh) * Nn + nq) * DHn + d] = f2bf(acc[i][j][r]);
            }
        }
    }
}

// 128x64 tile, register-free dbuf (N=768 -> 12 col-blocks, grid 768)
__global__ __launch_bounds__(256) void gemm_proj_kernel(
    const unsigned short* __restrict__ A,   // attnb 8192 x 768
    const unsigned short* __restrict__ BT,  // wprojT 768 x 768
    const float* __restrict__ bias,
    float* __restrict__ out) {
    constexpr int K = Ccn;
    const int bm = blockIdx.x, bn = blockIdx.y;
    const int t = threadIdx.x, wv = t >> 6, l = t & 63;
    const int fr = l & 15, quad = l >> 4;
    const int wm = (wv >> 1) * 64, wn = (wv & 1) * 32;
    __shared__ __align__(16) unsigned short As[2][128 * 32];
    __shared__ __align__(16) unsigned short Bs[2][64 * 32];
    const f32x4 zero = {0.f, 0.f, 0.f, 0.f};
    f32x4 acc[4][2];
#pragma unroll
    for (int i = 0; i < 4; ++i)
#pragma unroll
        for (int j = 0; j < 2; ++j) acc[i][j] = zero;

    const int srow = wv * 16 + (l >> 2);
    const int scol_dst = (l & 3) * 8;
    const int scol_src = (((l & 3) ^ ((srow >> 1) & 3)) << 3);
    const unsigned short* Ag = A + (size_t)(bm * 128 + srow) * K + scol_src;
    const int ldstA = srow * 32 + scol_dst;
    const int rB = t >> 2, cB = t & 3;                         // B tile: 64 rows x 4 chunks
    const int bsrc = ((cB ^ ((rB >> 1) & 3)) << 3);
    const unsigned short* Bg = BT + (size_t)(bn * 64 + rB) * K + bsrc;
    const int ldstB = rB * 32 + cB * 8;
    const int rsw = ((fr >> 1) & 3);

    auto stage = [&](int r, int bsel) {
        const unsigned short* Ar = Ag + r * 32;
        glds16(Ar, &As[bsel][ldstA]);
        glds16(Ar + (size_t)64 * K, &As[bsel][ldstA + 64 * 32]);
        glds16(Bg + r * 32, &Bs[bsel][ldstB]);
    };
    stage(0, 0);
    __syncthreads();
    for (int r = 0; r < 24; ++r) {
        if (r < 23) stage(r + 1, (r + 1) & 1);
        const unsigned short* Asb = As[r & 1];
        const unsigned short* Bsb = Bs[r & 1];
        bf16x8 af[4], bfv[2];
#pragma unroll
        for (int i = 0; i < 4; ++i)
            af[i] = *(const bf16x8*)&Asb[(wm + i * 16 + fr) * 32 + ((quad ^ rsw) << 3)];
#pragma unroll
        for (int j = 0; j < 2; ++j)
            bfv[j] = *(const bf16x8*)&Bsb[(wn + j * 16 + fr) * 32 + ((quad ^ rsw) << 3)];
#pragma unroll
        for (int i = 0; i < 4; ++i)
#pragma unroll
            for (int j = 0; j < 2; ++j)
                acc[i][j] = __builtin_amdgcn_mfma_f32_16x16x32_bf16(af[i], bfv[j], acc[i][j], 0, 0, 0);
        __syncthreads();
    }
#pragma unroll
    for (int j = 0; j < 2; ++j) {
        int col = bn * 64 + wn + j * 16 + fr;
        float bv = bias[col];
#pragma unroll
        for (int i = 0; i < 4; ++i) {
#pragma unroll
            for (int r = 0; r < 4; ++r) {
                int row = bm * 128 + wm + i * 16 + quad * 4 + r;
                out[(size_t)row * Ccn + col] = acc[i][j][r] + bv;
            }
        }
    }
}

// ---------------- fused flash attention (unchanged from R7) -------------------
// S^T formulation, no-max softmax, 64-key rounds, register-free double buffer.
__global__ __launch_bounds__(256, 3) void attn_fused(
    const unsigned short* __restrict__ qkvb,  // (3,B,H,N,64) bf16
    const unsigned short* __restrict__ vtb,   // (B,H,64,N) bf16
    const float* __restrict__ maskneg,        // (B,N): 0 keep, -1e9 masked
    unsigned short* __restrict__ attnb) {     // (B,N,H,64) bf16
    const int hb = blockIdx.x, qt = blockIdx.y;
    const int b = hb / Hh, h = hb - b * Hh;
    const int t = threadIdx.x, wv = t >> 6, l = t & 63;
    const int fr = l & 15, quad = l >> 4;
    __shared__ __align__(16) unsigned short Ks[2][64 * 64];
    __shared__ __align__(16) unsigned short VTs[2][64 * 64];
    __shared__ __align__(16) float Ms[2][64];
    __shared__ __align__(16) unsigned short Pbuf[4][16 * 72];
    const size_t bh = (size_t)b * Hh + h;
    const unsigned short* Qg = qkvb + bh * (Nn * DHn);
    const unsigned short* Kg = qkvb + (BHn + bh) * (Nn * DHn);
    const unsigned short* Vg = vtb + bh * (DHn * Nn);
    const float* Mg = maskneg + b * Nn;
    const int q0 = qt * 128 + wv * 32;

    // Q fragments for both 16-row groups, pre-scaled by Dh^-0.5 = 0.125 (exact)
    bf16x8 qf[2][2];
#pragma unroll
    for (int g = 0; g < 2; ++g)
#pragma unroll
        for (int c = 0; c < 2; ++c) {
            bf16x8 raw = *(const bf16x8*)&Qg[(size_t)(q0 + g * 16 + fr) * DHn + c * 32 + quad * 8];
            bf16x8 sc;
#pragma unroll
            for (int j = 0; j < 8; ++j)
                sc[j] = (short)f2bf(bf2f((unsigned short)raw[j]) * 0.125f);
            qf[g][c] = sc;
        }
    const f32x4 zero = {0.f, 0.f, 0.f, 0.f};
    f32x4 o[2][4];
    float rs[2] = {0.f, 0.f};
#pragma unroll
    for (int g = 0; g < 2; ++g)
#pragma unroll
        for (int r = 0; r < 4; ++r) o[g][r] = zero;

    const int srow = wv * 8 + (l >> 3);                       // 0..31
    const int lincol = (l & 7) * 8;                           // linear dest chunk
    const int swzcol = (((l & 7) ^ (srow & 7)) << 3);         // swizzled source chunk

    auto stage = [&](int kbase, int bsel) {
        glds16(&Kg[(size_t)(kbase + srow) * DHn + swzcol], &Ks[bsel][srow * 64 + lincol]);
        glds16(&Kg[(size_t)(kbase + srow + 32) * DHn + swzcol], &Ks[bsel][(srow + 32) * 64 + lincol]);
        glds16(&Vg[(size_t)srow * Nn + kbase + swzcol], &VTs[bsel][srow * 64 + lincol]);
        glds16(&Vg[(size_t)(srow + 32) * Nn + kbase + swzcol], &VTs[bsel][(srow + 32) * 64 + lincol]);
        if (t < 16) glds16(&Mg[kbase + t * 4], &Ms[bsel][t * 4]);
    };
    auto compute = [&](int bsel) {
        f32x4 ci[4];
#pragma unroll
        for (int kt = 0; kt < 4; ++kt)
            ci[kt] = *(const f32x4*)&Ms[bsel][kt * 16 + quad * 4];
        bf16x8 kf0[4], kf1[4];
#pragma unroll
        for (int kt = 0; kt < 4; ++kt) {
            int rr = kt * 16 + fr, sw = rr & 7;
            kf0[kt] = *(const bf16x8*)&Ks[bsel][rr * 64 + ((quad ^ sw) << 3)];
            kf1[kt] = *(const bf16x8*)&Ks[bsel][rr * 64 + (((quad + 4) ^ sw) << 3)];
        }
        f32x4 sg[2][4];
#pragma unroll
        for (int g = 0; g < 2; ++g)
#pragma unroll
            for (int kt = 0; kt < 4; ++kt) {
                f32x4 s = __builtin_amdgcn_mfma_f32_16x16x32_bf16(kf0[kt], qf[g][0], ci[kt], 0, 0, 0);
                sg[g][kt] = __builtin_amdgcn_mfma_f32_16x16x32_bf16(kf1[kt], qf[g][1], s, 0, 0, 0);
            }
        bf16x8 vf0[4], vf1[4];
#pragma unroll
        for (int dt = 0; dt < 4; ++dt) {
            int rr = dt * 16 + fr, sw = rr & 7;
            vf0[dt] = *(const bf16x8*)&VTs[bsel][rr * 64 + ((quad ^ sw) << 3)];
            vf1[dt] = *(const bf16x8*)&VTs[bsel][rr * 64 + (((quad + 4) ^ sw) << 3)];
        }
        unsigned short* Pw = Pbuf[wv];
#pragma unroll
        for (int g = 0; g < 2; ++g) {
#pragma unroll
            for (int kt = 0; kt < 4; ++kt) {
                float p0 = __expf(sg[g][kt][0]);
                float p1 = __expf(sg[g][kt][1]);
                float p2 = __expf(sg[g][kt][2]);
                float p3 = __expf(sg[g][kt][3]);
                rs[g] += (p0 + p1) + (p2 + p3);
                uint2 pk;
                pk.x = pack2bf(p0, p1);
                pk.y = pack2bf(p2, p3);
                *(uint2*)&Pw[fr * 72 + kt * 16 + quad * 4] = pk;
            }
            bf16x8 pa0 = *(const bf16x8*)&Pw[fr * 72 + quad * 8];
            bf16x8 pa1 = *(const bf16x8*)&Pw[fr * 72 + 32 + quad * 8];
#pragma unroll
            for (int dt = 0; dt < 4; ++dt) {
                f32x4 t0 = __builtin_amdgcn_mfma_f32_16x16x32_bf16(pa0, vf0[dt], o[g][dt], 0, 0, 0);
                o[g][dt] = __builtin_amdgcn_mfma_f32_16x16x32_bf16(pa1, vf1[dt], t0, 0, 0, 0);
            }
        }
    };

    stage(0, 0);
    __syncthreads();
    for (int r = 0; r < 16; ++r) {
        if (r < 15) stage((r + 1) * 64, (r + 1) & 1);
        compute(r & 1);
        __syncthreads();
    }
#pragma unroll
    for (int g = 0; g < 2; ++g) {
        float r2 = rs[g] + __shfl_xor(rs[g], 16, 64);
        float rfull = r2 + __shfl_xor(r2, 32, 64);   // valid for q = fr on all lanes
        float inv[4];
#pragma unroll
        for (int r = 0; r < 4; ++r) {
            float lv = __shfl(rfull, quad * 4 + r, 64);   // sum for q = quad*4+r
            inv[r] = (lv > 0.f) ? 1.0f / lv : 0.f;
        }
#pragma unroll
        for (int dt = 0; dt < 4; ++dt)
#pragma unroll
            for (int r = 0; r < 4; ++r) {
                int q = q0 + g * 16 + quad * 4 + r;
                attnb[((size_t)(b * Nn + q) * Hh + h) * DHn + dt * 16 + fr] = f2bf(o[g][dt][r] * inv[r]);
            }
    }
}

// ---------------- workspace layout (bytes, all 256-aligned) ----------------
#define OFF_XB     0u            // 8192*768*2   = 12,582,912
#define OFF_WQKVT  12582912u     // 2304*768*2   =  3,538,944
#define OFF_WPROJT 16121856u     // 768*768*2    =  1,179,648
#define OFF_MASKB  17301504u     // 8192*4       =     32,768
#define OFF_QKVB   17334272u     // 3*96*1024*64*2 = 37,748,736
#define OFF_VTB    55083008u     // 96*64*1024*2 = 12,582,912
#define OFF_ATTNB  67665920u     // 8192*768*2   = 12,582,912
// total 80,248,832 bytes

extern "C" void kernel_launch(void* const* d_in, const int* in_sizes, int n_in,
                              void* d_out, int out_size, void* d_ws, size_t ws_size,
                              hipStream_t stream) {
    const float* x      = (const float*)d_in[0];
    const int*   mask   = (const int*)d_in[1];
    const float* w_qkv  = (const float*)d_in[2];
    const float* w_proj = (const float*)d_in[3];
    const float* b_proj = (const float*)d_in[4];
    float* out = (float*)d_out;
    char* ws = (char*)d_ws;
    unsigned short* xb     = (unsigned short*)(ws + OFF_XB);
    unsigned short* wqkvT  = (unsigned short*)(ws + OFF_WQKVT);
    unsigned short* wprojT = (unsigned short*)(ws + OFF_WPROJT);
    float*          maskng = (float*)(ws + OFF_MASKB);
    unsigned short* qkvb   = (unsigned short*)(ws + OFF_QKVB);
    unsigned short* vtb    = (unsigned short*)(ws + OFF_VTB);
    unsigned short* attnb  = (unsigned short*)(ws + OFF_ATTNB);

    // all prep in one launch
    prep_kernel<<<dim3(5376), dim3(256), 0, stream>>>(x, xb, mask, maskng,
                                                      w_qkv, wqkvT, w_proj, wprojT);
    // qkv = x @ w_qkv  (scattered to (s,b,h,n,d) bf16)
    gemm_qkv_kernel<<<dim3(Mrows / 128, N3C / 128), dim3(256), 0, stream>>>(xb, wqkvT, qkvb);
    // V -> V^T per (b,h)
    transpose_v_kernel<<<dim3(DHn / 32, Nn / 32, BHn), dim3(32, 8), 0, stream>>>(
        qkvb + (size_t)2 * BHn * Nn * DHn, vtb);
    // fused masked flash attention: grid (pairs, q-tiles) for XCD L2 locality
    attn_fused<<<dim3(BHn, Nn / 128), dim3(256), 0, stream>>>(qkvb, vtb, maskng, attnb);
    // out = attn @ w_proj + b
    gemm_proj_kernel<<<dim3(Mrows / 128, Ccn / 64), dim3(256), 0, stream>>>(attnb, wprojT, b_proj, out);
}

// Round 9
// 193.817 us; speedup vs baseline: 1.0328x; 1.0328x over previous
//
#include <hip/hip_runtime.h>
#include <cstdint>
#include <cstddef>

// ---------------- problem constants ----------------
#define Bb   8
#define Nn   1024
#define Ccn  768
#define Hh   12
#define DHn  64
#define Mrows (Bb * Nn)   // 8192
#define N3C  (3 * Ccn)    // 2304
#define BHn  (Bb * Hh)    // 96

typedef __attribute__((ext_vector_type(8))) short bf16x8;   // 8 bf16 (4 VGPRs)
typedef __attribute__((ext_vector_type(4))) float f32x4;

static __device__ __forceinline__ unsigned short f2bf(float f) {
    unsigned int u = __builtin_bit_cast(unsigned int, f);
    return (unsigned short)((u + 0x7FFFu + ((u >> 16) & 1u)) >> 16);  // RNE
}
static __device__ __forceinline__ float bf2f(unsigned short s) {
    unsigned int u = ((unsigned int)s) << 16;
    return __builtin_bit_cast(float, u);
}
// pack two f32 -> two bf16 (round half-up; inputs are finite non-negative p's)
static __device__ __forceinline__ unsigned pack2bf(float a, float b) {
    unsigned ua = __builtin_bit_cast(unsigned, a) + 0x8000u;
    unsigned ub = __builtin_bit_cast(unsigned, b) + 0x8000u;
    return (ua >> 16) | (ub & 0xFFFF0000u);
}
// async global->LDS, 16B per lane; LDS dest must be (wave-uniform base + lane*16)
static __device__ __forceinline__ void glds16(const void* g, void* l) {
    __builtin_amdgcn_global_load_lds((const __attribute__((address_space(1))) void*)g,
                                     (__attribute__((address_space(3))) void*)l,
                                     16, 0, 0);
}

// ---------------- merged prep kernel ----------------
// blocks [0,3072): x fp32->bf16 + mask->(0/-1e9)
// blocks [3072,5376): both weight transposes (96 x 24 tile grid flattened)
__global__ void prep_kernel(const float* __restrict__ x,
                            unsigned short* __restrict__ xb,
                            const int* __restrict__ mask,
                            float* __restrict__ maskneg,
                            const float* __restrict__ Wqkv,
                            unsigned short* __restrict__ WqkvT,
                            const float* __restrict__ Wproj,
                            unsigned short* __restrict__ WprojT) {
    __shared__ float tile[32][33];
    int bx = blockIdx.x;
    if (bx < 3072) {
        int i = bx * 256 + threadIdx.x;
        if (i < Mrows) maskneg[i] = (mask[i] != 0) ? -1.0e9f : 0.0f;
        const f32x4* xp = (const f32x4*)x;
        f32x4 a = xp[2 * i], b = xp[2 * i + 1];
        bf16x8 v;
#pragma unroll
        for (int j = 0; j < 4; ++j) {
            v[j]     = (short)f2bf(a[j]);
            v[4 + j] = (short)f2bf(b[j]);
        }
        ((bf16x8*)xb)[i] = v;
        return;
    }
    bx -= 3072;
    int xt = bx % 96, yt = bx / 96;
    const float* W; unsigned short* WT; int C;
    if (xt < 72) { W = Wqkv;  WT = WqkvT;  C = N3C; }
    else         { W = Wproj; WT = WprojT; C = Ccn; xt -= 72; }
    const int R = Ccn;
    const int c0 = xt * 32, r0 = yt * 32;
    const int tx = threadIdx.x & 31, ty = threadIdx.x >> 5;
#pragma unroll
    for (int i = 0; i < 4; ++i)
        tile[ty + i * 8][tx] = W[(size_t)(r0 + ty + i * 8) * C + c0 + tx];
    __syncthreads();
#pragma unroll
    for (int i = 0; i < 4; ++i)
        WT[(size_t)(c0 + ty + i * 8) * R + r0 + tx] = f2bf(tile[tx][ty + i * 8]);
}

// per (b,h): V (1024 x 64) bf16 -> VT (64 x 1024) bf16
__global__ void transpose_v_kernel(const unsigned short* __restrict__ vb,
                                   unsigned short* __restrict__ vtb) {
    __shared__ unsigned short tile[32][34];
    const int bh = blockIdx.z;
    const int d0 = blockIdx.x * 32, n0 = blockIdx.y * 32;
    const int tx = threadIdx.x, ty = threadIdx.y;
    const unsigned short* src = vb + (size_t)bh * Nn * DHn;
    unsigned short* dst = vtb + (size_t)bh * DHn * Nn;
#pragma unroll
    for (int i = 0; i < 4; ++i)
        tile[ty + i * 8][tx] = src[(size_t)(n0 + ty + i * 8) * DHn + d0 + tx];
    __syncthreads();
#pragma unroll
    for (int i = 0; i < 4; ++i)
        dst[(size_t)(d0 + ty + i * 8) * Nn + n0 + tx] = tile[tx][ty + i * 8];
}

// ---- bf16 GEMM, 128x128 tile, BK=64, single buffer, attn-style XOR swizzle ----
// LDS rows are 64 bf16 (8 chunks of 16B); chunk c of row r stored at slot
// c ^ (r&7) -> staging stays lane-contiguous in LDS (global src swizzled),
// fragment ds_read_b128 are <=2-way banked (free). 12 iters, 32 MFMA/barrier.
__global__ __launch_bounds__(256) void gemm_qkv_kernel(
    const unsigned short* __restrict__ A,
    const unsigned short* __restrict__ BT,
    unsigned short* __restrict__ qkvb) {
    constexpr int K = Ccn;
    const int bm = blockIdx.x, bn = blockIdx.y;
    const int t = threadIdx.x, wv = t >> 6, l = t & 63;
    const int fr = l & 15, quad = l >> 4;
    const int wm = (wv >> 1) * 64, wn = (wv & 1) * 64;
    __shared__ __align__(16) unsigned short As[128 * 64];
    __shared__ __align__(16) unsigned short Bs[128 * 64];
    const f32x4 zero = {0.f, 0.f, 0.f, 0.f};
    f32x4 acc[4][4];
#pragma unroll
    for (int i = 0; i < 4; ++i)
#pragma unroll
        for (int j = 0; j < 4; ++j) acc[i][j] = zero;

    const int srow = t >> 3;                       // 0..31
    const int c8 = t & 7;                          // dest chunk slot
    const int lincol = c8 * 8;
    const int swz = ((c8 ^ (srow & 7)) << 3);      // swizzled source chunk
    const unsigned short* Ag = A + (size_t)(bm * 128 + srow) * K + swz;
    const unsigned short* Bg = BT + (size_t)(bn * 128 + srow) * K + swz;

    for (int k0 = 0; k0 < K; k0 += 64) {
#pragma unroll
        for (int hh = 0; hh < 4; ++hh) {
            glds16(Ag + (size_t)(32 * hh) * K + k0, &As[(srow + 32 * hh) * 64 + lincol]);
            glds16(Bg + (size_t)(32 * hh) * K + k0, &Bs[(srow + 32 * hh) * 64 + lincol]);
        }
        __syncthreads();
#pragma unroll
        for (int s = 0; s < 2; ++s) {
            bf16x8 af[4], bfv[4];
#pragma unroll
            for (int i = 0; i < 4; ++i) {
                int rr = wm + i * 16 + fr;
                af[i] = *(const bf16x8*)&As[rr * 64 + (((s * 4 + quad) ^ (rr & 7)) << 3)];
            }
#pragma unroll
            for (int j = 0; j < 4; ++j) {
                int rr = wn + j * 16 + fr;
                bfv[j] = *(const bf16x8*)&Bs[rr * 64 + (((s * 4 + quad) ^ (rr & 7)) << 3)];
            }
#pragma unroll
            for (int i = 0; i < 4; ++i)
#pragma unroll
                for (int j = 0; j < 4; ++j)
                    acc[i][j] = __builtin_amdgcn_mfma_f32_16x16x32_bf16(af[i], bfv[j], acc[i][j], 0, 0, 0);
        }
        __syncthreads();
    }
    // epilogue: C row = bm*128+wm+i*16+quad*4+r ; col = bn*128+wn+j*16+fr -> (s,h,d)
#pragma unroll
    for (int j = 0; j < 4; ++j) {
        int col = bn * 128 + wn + j * 16 + fr;
        int s = col / Ccn;
        int rem = col - s * Ccn;
        int hh = rem >> 6, d = rem & 63;
#pragma unroll
        for (int i = 0; i < 4; ++i) {
#pragma unroll
            for (int r = 0; r < 4; ++r) {
                int row = bm * 128 + wm + i * 16 + quad * 4 + r;
                int b = row >> 10, nq = row & 1023;
                qkvb[((((size_t)s * Bb + b) * Hh + hh) * Nn + nq) * DHn + d] = f2bf(acc[i][j][r]);
            }
        }
    }
}

// 128x64 tile, BK=64 single buffer (N=768 -> 12 col-blocks, grid 768)
__global__ __launch_bounds__(256) void gemm_proj_kernel(
    const unsigned short* __restrict__ A,   // attnb 8192 x 768
    const unsigned short* __restrict__ BT,  // wprojT 768 x 768
    const float* __restrict__ bias,
    float* __restrict__ out) {
    constexpr int K = Ccn;
    const int bm = blockIdx.x, bn = blockIdx.y;
    const int t = threadIdx.x, wv = t >> 6, l = t & 63;
    const int fr = l & 15, quad = l >> 4;
    const int wm = (wv >> 1) * 64, wn = (wv & 1) * 32;
    __shared__ __align__(16) unsigned short As[128 * 64];
    __shared__ __align__(16) unsigned short Bs[64 * 64];
    const f32x4 zero = {0.f, 0.f, 0.f, 0.f};
    f32x4 acc[4][2];
#pragma unroll
    for (int i = 0; i < 4; ++i)
#pragma unroll
        for (int j = 0; j < 2; ++j) acc[i][j] = zero;

    const int srow = t >> 3;                       // 0..31
    const int c8 = t & 7;
    const int lincol = c8 * 8;
    const int swz = ((c8 ^ (srow & 7)) << 3);
    const unsigned short* Ag = A + (size_t)(bm * 128 + srow) * K + swz;
    const unsigned short* Bg = BT + (size_t)(bn * 64 + srow) * K + swz;

    for (int k0 = 0; k0 < K; k0 += 64) {
#pragma unroll
        for (int hh = 0; hh < 4; ++hh)
            glds16(Ag + (size_t)(32 * hh) * K + k0, &As[(srow + 32 * hh) * 64 + lincol]);
#pragma unroll
        for (int hh = 0; hh < 2; ++hh)
            glds16(Bg + (size_t)(32 * hh) * K + k0, &Bs[(srow + 32 * hh) * 64 + lincol]);
        __syncthreads();
#pragma unroll
        for (int s = 0; s < 2; ++s) {
            bf16x8 af[4], bfv[2];
#pragma unroll
            for (int i = 0; i < 4; ++i) {
                int rr = wm + i * 16 + fr;
                af[i] = *(const bf16x8*)&As[rr * 64 + (((s * 4 + quad) ^ (rr & 7)) << 3)];
            }
#pragma unroll
            for (int j = 0; j < 2; ++j) {
                int rr = wn + j * 16 + fr;
                bfv[j] = *(const bf16x8*)&Bs[rr * 64 + (((s * 4 + quad) ^ (rr & 7)) << 3)];
            }
#pragma unroll
            for (int i = 0; i < 4; ++i)
#pragma unroll
                for (int j = 0; j < 2; ++j)
                    acc[i][j] = __builtin_amdgcn_mfma_f32_16x16x32_bf16(af[i], bfv[j], acc[i][j], 0, 0, 0);
        }
        __syncthreads();
    }
#pragma unroll
    for (int j = 0; j < 2; ++j) {
        int col = bn * 64 + wn + j * 16 + fr;
        float bv = bias[col];
#pragma unroll
        for (int i = 0; i < 4; ++i) {
#pragma unroll
            for (int r = 0; r < 4; ++r) {
                int row = bm * 128 + wm + i * 16 + quad * 4 + r;
                out[(size_t)row * Ccn + col] = acc[i][j][r] + bv;
            }
        }
    }
}

// ---------------- fused flash attention (unchanged from R7) -------------------
// S^T formulation, no-max softmax, 64-key rounds, register-free double buffer.
__global__ __launch_bounds__(256, 3) void attn_fused(
    const unsigned short* __restrict__ qkvb,  // (3,B,H,N,64) bf16
    const unsigned short* __restrict__ vtb,   // (B,H,64,N) bf16
    const float* __restrict__ maskneg,        // (B,N): 0 keep, -1e9 masked
    unsigned short* __restrict__ attnb) {     // (B,N,H,64) bf16
    const int hb = blockIdx.x, qt = blockIdx.y;
    const int b = hb / Hh, h = hb - b * Hh;
    const int t = threadIdx.x, wv = t >> 6, l = t & 63;
    const int fr = l & 15, quad = l >> 4;
    __shared__ __align__(16) unsigned short Ks[2][64 * 64];
    __shared__ __align__(16) unsigned short VTs[2][64 * 64];
    __shared__ __align__(16) float Ms[2][64];
    __shared__ __align__(16) unsigned short Pbuf[4][16 * 72];
    const size_t bh = (size_t)b * Hh + h;
    const unsigned short* Qg = qkvb + bh * (Nn * DHn);
    const unsigned short* Kg = qkvb + (BHn + bh) * (Nn * DHn);
    const unsigned short* Vg = vtb + bh * (DHn * Nn);
    const float* Mg = maskneg + b * Nn;
    const int q0 = qt * 128 + wv * 32;

    // Q fragments for both 16-row groups, pre-scaled by Dh^-0.5 = 0.125 (exact)
    bf16x8 qf[2][2];
#pragma unroll
    for (int g = 0; g < 2; ++g)
#pragma unroll
        for (int c = 0; c < 2; ++c) {
            bf16x8 raw = *(const bf16x8*)&Qg[(size_t)(q0 + g * 16 + fr) * DHn + c * 32 + quad * 8];
            bf16x8 sc;
#pragma unroll
            for (int j = 0; j < 8; ++j)
                sc[j] = (short)f2bf(bf2f((unsigned short)raw[j]) * 0.125f);
            qf[g][c] = sc;
        }
    const f32x4 zero = {0.f, 0.f, 0.f, 0.f};
    f32x4 o[2][4];
    float rs[2] = {0.f, 0.f};
#pragma unroll
    for (int g = 0; g < 2; ++g)
#pragma unroll
        for (int r = 0; r < 4; ++r) o[g][r] = zero;

    const int srow = wv * 8 + (l >> 3);                       // 0..31
    const int lincol = (l & 7) * 8;                           // linear dest chunk
    const int swzcol = (((l & 7) ^ (srow & 7)) << 3);         // swizzled source chunk

    auto stage = [&](int kbase, int bsel) {
        glds16(&Kg[(size_t)(kbase + srow) * DHn + swzcol], &Ks[bsel][srow * 64 + lincol]);
        glds16(&Kg[(size_t)(kbase + srow + 32) * DHn + swzcol], &Ks[bsel][(srow + 32) * 64 + lincol]);
        glds16(&Vg[(size_t)srow * Nn + kbase + swzcol], &VTs[bsel][srow * 64 + lincol]);
        glds16(&Vg[(size_t)(srow + 32) * Nn + kbase + swzcol], &VTs[bsel][(srow + 32) * 64 + lincol]);
        if (t < 16) glds16(&Mg[kbase + t * 4], &Ms[bsel][t * 4]);
    };
    auto compute = [&](int bsel) {
        f32x4 ci[4];
#pragma unroll
        for (int kt = 0; kt < 4; ++kt)
            ci[kt] = *(const f32x4*)&Ms[bsel][kt * 16 + quad * 4];
        bf16x8 kf0[4], kf1[4];
#pragma unroll
        for (int kt = 0; kt < 4; ++kt) {
            int rr = kt * 16 + fr, sw = rr & 7;
            kf0[kt] = *(const bf16x8*)&Ks[bsel][rr * 64 + ((quad ^ sw) << 3)];
            kf1[kt] = *(const bf16x8*)&Ks[bsel][rr * 64 + (((quad + 4) ^ sw) << 3)];
        }
        f32x4 sg[2][4];
#pragma unroll
        for (int g = 0; g < 2; ++g)
#pragma unroll
            for (int kt = 0; kt < 4; ++kt) {
                f32x4 s = __builtin_amdgcn_mfma_f32_16x16x32_bf16(kf0[kt], qf[g][0], ci[kt], 0, 0, 0);
                sg[g][kt] = __builtin_amdgcn_mfma_f32_16x16x32_bf16(kf1[kt], qf[g][1], s, 0, 0, 0);
            }
        bf16x8 vf0[4], vf1[4];
#pragma unroll
        for (int dt = 0; dt < 4; ++dt) {
            int rr = dt * 16 + fr, sw = rr & 7;
            vf0[dt] = *(const bf16x8*)&VTs[bsel][rr * 64 + ((quad ^ sw) << 3)];
            vf1[dt] = *(const bf16x8*)&VTs[bsel][rr * 64 + (((quad + 4) ^ sw) << 3)];
        }
        unsigned short* Pw = Pbuf[wv];
#pragma unroll
        for (int g = 0; g < 2; ++g) {
#pragma unroll
            for (int kt = 0; kt < 4; ++kt) {
                float p0 = __expf(sg[g][kt][0]);
                float p1 = __expf(sg[g][kt][1]);
                float p2 = __expf(sg[g][kt][2]);
                float p3 = __expf(sg[g][kt][3]);
                rs[g] += (p0 + p1) + (p2 + p3);
                uint2 pk;
                pk.x = pack2bf(p0, p1);
                pk.y = pack2bf(p2, p3);
                *(uint2*)&Pw[fr * 72 + kt * 16 + quad * 4] = pk;
            }
            bf16x8 pa0 = *(const bf16x8*)&Pw[fr * 72 + quad * 8];
            bf16x8 pa1 = *(const bf16x8*)&Pw[fr * 72 + 32 + quad * 8];
#pragma unroll
            for (int dt = 0; dt < 4; ++dt) {
                f32x4 t0 = __builtin_amdgcn_mfma_f32_16x16x32_bf16(pa0, vf0[dt], o[g][dt], 0, 0, 0);
                o[g][dt] = __builtin_amdgcn_mfma_f32_16x16x32_bf16(pa1, vf1[dt], t0, 0, 0, 0);
            }
        }
    };

    stage(0, 0);
    __syncthreads();
    for (int r = 0; r < 16; ++r) {
        if (r < 15) stage((r + 1) * 64, (r + 1) & 1);
        compute(r & 1);
        __syncthreads();
    }
#pragma unroll
    for (int g = 0; g < 2; ++g) {
        float r2 = rs[g] + __shfl_xor(rs[g], 16, 64);
        float rfull = r2 + __shfl_xor(r2, 32, 64);   // valid for q = fr on all lanes
        float inv[4];
#pragma unroll
        for (int r = 0; r < 4; ++r) {
            float lv = __shfl(rfull, quad * 4 + r, 64);   // sum for q = quad*4+r
            inv[r] = (lv > 0.f) ? 1.0f / lv : 0.f;
        }
#pragma unroll
        for (int dt = 0; dt < 4; ++dt)
#pragma unroll
            for (int r = 0; r < 4; ++r) {
                int q = q0 + g * 16 + quad * 4 + r;
                attnb[((size_t)(b * Nn + q) * Hh + h) * DHn + dt * 16 + fr] = f2bf(o[g][dt][r] * inv[r]);
            }
    }
}

// ---------------- workspace layout (bytes, all 256-aligned) ----------------
#define OFF_XB     0u            // 8192*768*2   = 12,582,912
#define OFF_WQKVT  12582912u     // 2304*768*2   =  3,538,944
#define OFF_WPROJT 16121856u     // 768*768*2    =  1,179,648
#define OFF_MASKB  17301504u     // 8192*4       =     32,768
#define OFF_QKVB   17334272u     // 3*96*1024*64*2 = 37,748,736
#define OFF_VTB    55083008u     // 96*64*1024*2 = 12,582,912
#define OFF_ATTNB  67665920u     // 8192*768*2   = 12,582,912
// total 80,248,832 bytes

extern "C" void kernel_launch(void* const* d_in, const int* in_sizes, int n_in,
                              void* d_out, int out_size, void* d_ws, size_t ws_size,
                              hipStream_t stream) {
    const float* x      = (const float*)d_in[0];
    const int*   mask   = (const int*)d_in[1];
    const float* w_qkv  = (const float*)d_in[2];
    const float* w_proj = (const float*)d_in[3];
    const float* b_proj = (const float*)d_in[4];
    float* out = (float*)d_out;
    char* ws = (char*)d_ws;
    unsigned short* xb     = (unsigned short*)(ws + OFF_XB);
    unsigned short* wqkvT  = (unsigned short*)(ws + OFF_WQKVT);
    unsigned short* wprojT = (unsigned short*)(ws + OFF_WPROJT);
    float*          maskng = (float*)(ws + OFF_MASKB);
    unsigned short* qkvb   = (unsigned short*)(ws + OFF_QKVB);
    unsigned short* vtb    = (unsigned short*)(ws + OFF_VTB);
    unsigned short* attnb  = (unsigned short*)(ws + OFF_ATTNB);

    // all prep in one launch
    prep_kernel<<<dim3(5376), dim3(256), 0, stream>>>(x, xb, mask, maskng,
                                                      w_qkv, wqkvT, w_proj, wprojT);
    // qkv = x @ w_qkv  (scattered to (s,b,h,n,d) bf16)
    gemm_qkv_kernel<<<dim3(Mrows / 128, N3C / 128), dim3(256), 0, stream>>>(xb, wqkvT, qkvb);
    // V -> V^T per (b,h)
    transpose_v_kernel<<<dim3(DHn / 32, Nn / 32, BHn), dim3(32, 8), 0, stream>>>(
        qkvb + (size_t)2 * BHn * Nn * DHn, vtb);
    // fused masked flash attention: grid (pairs, q-tiles) for XCD L2 locality
    attn_fused<<<dim3(BHn, Nn / 128), dim3(256), 0, stream>>>(qkvb, vtb, maskng, attnb);
    // out = attn @ w_proj + b
    gemm_proj_kernel<<<dim3(Mrows / 128, Ccn / 64), dim3(256), 0, stream>>>(attnb, wprojT, b_proj, out);
}

// Round 10
// 185.715 us; speedup vs baseline: 1.0779x; 1.0436x over previous
//
#include <hip/hip_runtime.h>
#include <cstdint>
#include <cstddef>

// ---------------- problem constants ----------------
#define Bb   8
#define Nn   1024
#define Ccn  768
#define Hh   12
#define DHn  64
#define Mrows (Bb * Nn)   // 8192
#define N3C  (3 * Ccn)    // 2304
#define BHn  (Bb * Hh)    // 96

typedef __attribute__((ext_vector_type(8))) short bf16x8;   // 8 bf16 (4 VGPRs)
typedef __attribute__((ext_vector_type(4))) float f32x4;

static __device__ __forceinline__ unsigned short f2bf(float f) {
    unsigned int u = __builtin_bit_cast(unsigned int, f);
    return (unsigned short)((u + 0x7FFFu + ((u >> 16) & 1u)) >> 16);  // RNE
}
static __device__ __forceinline__ float bf2f(unsigned short s) {
    unsigned int u = ((unsigned int)s) << 16;
    return __builtin_bit_cast(float, u);
}
// pack two f32 -> two bf16 (round half-up; inputs are finite non-negative p's)
static __device__ __forceinline__ unsigned pack2bf(float a, float b) {
    unsigned ua = __builtin_bit_cast(unsigned, a) + 0x8000u;
    unsigned ub = __builtin_bit_cast(unsigned, b) + 0x8000u;
    return (ua >> 16) | (ub & 0xFFFF0000u);
}
// async global->LDS, 16B per lane; LDS dest must be (wave-uniform base + lane*16)
static __device__ __forceinline__ void glds16(const void* g, void* l) {
    __builtin_amdgcn_global_load_lds((const __attribute__((address_space(1))) void*)g,
                                     (__attribute__((address_space(3))) void*)l,
                                     16, 0, 0);
}

// ---------------- merged prep kernel ----------------
// blocks [0,3072): x fp32->bf16 + mask->(0/-1e9)
// blocks [3072,5376): both weight transposes (96 x 24 tile grid flattened)
__global__ void prep_kernel(const float* __restrict__ x,
                            unsigned short* __restrict__ xb,
                            const int* __restrict__ mask,
                            float* __restrict__ maskneg,
                            const float* __restrict__ Wqkv,
                            unsigned short* __restrict__ WqkvT,
                            const float* __restrict__ Wproj,
                            unsigned short* __restrict__ WprojT) {
    __shared__ float tile[32][33];
    int bx = blockIdx.x;
    if (bx < 3072) {
        int i = bx * 256 + threadIdx.x;
        if (i < Mrows) maskneg[i] = (mask[i] != 0) ? -1.0e9f : 0.0f;
        const f32x4* xp = (const f32x4*)x;
        f32x4 a = xp[2 * i], b = xp[2 * i + 1];
        bf16x8 v;
#pragma unroll
        for (int j = 0; j < 4; ++j) {
            v[j]     = (short)f2bf(a[j]);
            v[4 + j] = (short)f2bf(b[j]);
        }
        ((bf16x8*)xb)[i] = v;
        return;
    }
    bx -= 3072;
    int xt = bx % 96, yt = bx / 96;
    const float* W; unsigned short* WT; int C;
    if (xt < 72) { W = Wqkv;  WT = WqkvT;  C = N3C; }
    else         { W = Wproj; WT = WprojT; C = Ccn; xt -= 72; }
    const int R = Ccn;
    const int c0 = xt * 32, r0 = yt * 32;
    const int tx = threadIdx.x & 31, ty = threadIdx.x >> 5;
#pragma unroll
    for (int i = 0; i < 4; ++i)
        tile[ty + i * 8][tx] = W[(size_t)(r0 + ty + i * 8) * C + c0 + tx];
    __syncthreads();
#pragma unroll
    for (int i = 0; i < 4; ++i)
        WT[(size_t)(c0 + ty + i * 8) * R + r0 + tx] = f2bf(tile[tx][ty + i * 8]);
}

// ---- bf16 GEMM, 128x128 tile, BK=32, swizzled LDS (R7-proven structure) ----
// Epilogue: Q/K columns -> qkvb (s,b,h,n,d); V columns (s==2) are written
// DIRECTLY TRANSPOSED to vtb (b,h,d,n) -- eliminates the transpose_v kernel.
__global__ __launch_bounds__(256) void gemm_qkv_kernel(
    const unsigned short* __restrict__ A,
    const unsigned short* __restrict__ BT,
    unsigned short* __restrict__ qkvb,
    unsigned short* __restrict__ vtb) {
    constexpr int K = Ccn;
    const int bm = blockIdx.x, bn = blockIdx.y;
    const int t = threadIdx.x, wv = t >> 6, l = t & 63;
    const int fr = l & 15, quad = l >> 4;
    const int wm = (wv >> 1) * 64, wn = (wv & 1) * 64;
    __shared__ __align__(16) unsigned short As[128 * 32];
    __shared__ __align__(16) unsigned short Bs[128 * 32];
    const f32x4 zero = {0.f, 0.f, 0.f, 0.f};
    f32x4 acc[4][4];
#pragma unroll
    for (int i = 0; i < 4; ++i)
#pragma unroll
        for (int j = 0; j < 4; ++j) acc[i][j] = zero;

    const int srow = wv * 16 + (l >> 2);                        // 0..63
    const int scol_dst = (l & 3) * 8;                           // linear dest chunk
    const int scol_src = (((l & 3) ^ ((srow >> 1) & 3)) << 3);  // swizzled source chunk
    const unsigned short* Ag = A + (size_t)(bm * 128 + srow) * K + scol_src;
    const unsigned short* Bg = BT + (size_t)(bn * 128 + srow) * K + scol_src;
    unsigned short* Al = &As[srow * 32 + scol_dst];
    unsigned short* Bl = &Bs[srow * 32 + scol_dst];
    const int rsw = ((fr >> 1) & 3);                            // read-side swizzle

    for (int k0 = 0; k0 < K; k0 += 32) {
        glds16(Ag, Al);
        glds16(Ag + (size_t)64 * K, Al + 64 * 32);
        glds16(Bg, Bl);
        glds16(Bg + (size_t)64 * K, Bl + 64 * 32);
        Ag += 32; Bg += 32;
        __syncthreads();
        bf16x8 af[4], bfv[4];
#pragma unroll
        for (int i = 0; i < 4; ++i)
            af[i] = *(const bf16x8*)&As[(wm + i * 16 + fr) * 32 + ((quad ^ rsw) << 3)];
#pragma unroll
        for (int i = 0; i < 4; ++i)
            bfv[i] = *(const bf16x8*)&Bs[(wn + i * 16 + fr) * 32 + ((quad ^ rsw) << 3)];
#pragma unroll
        for (int i = 0; i < 4; ++i)
#pragma unroll
            for (int j = 0; j < 4; ++j)
                acc[i][j] = __builtin_amdgcn_mfma_f32_16x16x32_bf16(af[i], bfv[j], acc[i][j], 0, 0, 0);
        __syncthreads();
    }
    // epilogue: C row = bm*128+wm+i*16+quad*4+r ; col = bn*128+wn+j*16+fr
#pragma unroll
    for (int j = 0; j < 4; ++j) {
        int col = bn * 128 + wn + j * 16 + fr;
        int s = col / Ccn;                 // wave-uniform per j (16-col group)
        int rem = col - s * Ccn;
        int hh = rem >> 6, d = rem & 63;
        if (s == 2) {
            // V: store transposed -> vtb[(b*H+h)*64 + d][nq]
#pragma unroll
            for (int i = 0; i < 4; ++i) {
#pragma unroll
                for (int r = 0; r < 4; ++r) {
                    int row = bm * 128 + wm + i * 16 + quad * 4 + r;
                    int b = row >> 10, nq = row & 1023;
                    vtb[(((size_t)(b * Hh + hh)) * DHn + d) * Nn + nq] = f2bf(acc[i][j][r]);
                }
            }
        } else {
#pragma unroll
            for (int i = 0; i < 4; ++i) {
#pragma unroll
                for (int r = 0; r < 4; ++r) {
                    int row = bm * 128 + wm + i * 16 + quad * 4 + r;
                    int b = row >> 10, nq = row & 1023;
                    qkvb[((((size_t)s * Bb + b) * Hh + hh) * Nn + nq) * DHn + d] = f2bf(acc[i][j][r]);
                }
            }
        }
    }
}

// 128x64 tile, BK=32 single buffer (N=768 -> 12 col-blocks, grid 768)
__global__ __launch_bounds__(256) void gemm_proj_kernel(
    const unsigned short* __restrict__ A,   // attnb 8192 x 768
    const unsigned short* __restrict__ BT,  // wprojT 768 x 768
    const float* __restrict__ bias,
    float* __restrict__ out) {
    constexpr int K = Ccn;
    const int bm = blockIdx.x, bn = blockIdx.y;
    const int t = threadIdx.x, wv = t >> 6, l = t & 63;
    const int fr = l & 15, quad = l >> 4;
    const int wm = (wv >> 1) * 64, wn = (wv & 1) * 32;
    __shared__ __align__(16) unsigned short As[128 * 32];
    __shared__ __align__(16) unsigned short Bs[64 * 32];
    const f32x4 zero = {0.f, 0.f, 0.f, 0.f};
    f32x4 acc[4][2];
#pragma unroll
    for (int i = 0; i < 4; ++i)
#pragma unroll
        for (int j = 0; j < 2; ++j) acc[i][j] = zero;

    const int srow = wv * 16 + (l >> 2);
    const int scol_dst = (l & 3) * 8;
    const int scol_src = (((l & 3) ^ ((srow >> 1) & 3)) << 3);
    const unsigned short* Ag = A + (size_t)(bm * 128 + srow) * K + scol_src;
    unsigned short* Al = &As[srow * 32 + scol_dst];
    const int rB = t >> 2, cB = t & 3;                         // B tile: 64 rows x 4 chunks
    const int bsrc = ((cB ^ ((rB >> 1) & 3)) << 3);
    const unsigned short* Bg = BT + (size_t)(bn * 64 + rB) * K + bsrc;
    unsigned short* Bl = &Bs[rB * 32 + cB * 8];
    const int rsw = ((fr >> 1) & 3);

    for (int k0 = 0; k0 < K; k0 += 32) {
        glds16(Ag, Al);
        glds16(Ag + (size_t)64 * K, Al + 64 * 32);
        glds16(Bg, Bl);
        Ag += 32; Bg += 32;
        __syncthreads();
        bf16x8 af[4], bfv[2];
#pragma unroll
        for (int i = 0; i < 4; ++i)
            af[i] = *(const bf16x8*)&As[(wm + i * 16 + fr) * 32 + ((quad ^ rsw) << 3)];
#pragma unroll
        for (int j = 0; j < 2; ++j)
            bfv[j] = *(const bf16x8*)&Bs[(wn + j * 16 + fr) * 32 + ((quad ^ rsw) << 3)];
#pragma unroll
        for (int i = 0; i < 4; ++i)
#pragma unroll
            for (int j = 0; j < 2; ++j)
                acc[i][j] = __builtin_amdgcn_mfma_f32_16x16x32_bf16(af[i], bfv[j], acc[i][j], 0, 0, 0);
        __syncthreads();
    }
#pragma unroll
    for (int j = 0; j < 2; ++j) {
        int col = bn * 64 + wn + j * 16 + fr;
        float bv = bias[col];
#pragma unroll
        for (int i = 0; i < 4; ++i) {
#pragma unroll
            for (int r = 0; r < 4; ++r) {
                int row = bm * 128 + wm + i * 16 + quad * 4 + r;
                out[(size_t)row * Ccn + col] = acc[i][j][r] + bv;
            }
        }
    }
}

// ---------------- fused flash attention (R7-proven form, unchanged) -----------
// S^T formulation, no-max softmax, 64-key rounds, register-free double buffer.
__global__ __launch_bounds__(256, 3) void attn_fused(
    const unsigned short* __restrict__ qkvb,  // (3,B,H,N,64) bf16 (s=0,1 used)
    const unsigned short* __restrict__ vtb,   // (B,H,64,N) bf16
    const float* __restrict__ maskneg,        // (B,N): 0 keep, -1e9 masked
    unsigned short* __restrict__ attnb) {     // (B,N,H,64) bf16
    const int hb = blockIdx.x, qt = blockIdx.y;
    const int b = hb / Hh, h = hb - b * Hh;
    const int t = threadIdx.x, wv = t >> 6, l = t & 63;
    const int fr = l & 15, quad = l >> 4;
    __shared__ __align__(16) unsigned short Ks[2][64 * 64];
    __shared__ __align__(16) unsigned short VTs[2][64 * 64];
    __shared__ __align__(16) float Ms[2][64];
    __shared__ __align__(16) unsigned short Pbuf[4][16 * 72];
    const size_t bh = (size_t)b * Hh + h;
    const unsigned short* Qg = qkvb + bh * (Nn * DHn);
    const unsigned short* Kg = qkvb + (BHn + bh) * (Nn * DHn);
    const unsigned short* Vg = vtb + bh * (DHn * Nn);
    const float* Mg = maskneg + b * Nn;
    const int q0 = qt * 128 + wv * 32;

    // Q fragments for both 16-row groups, pre-scaled by Dh^-0.5 = 0.125 (exact)
    bf16x8 qf[2][2];
#pragma unroll
    for (int g = 0; g < 2; ++g)
#pragma unroll
        for (int c = 0; c < 2; ++c) {
            bf16x8 raw = *(const bf16x8*)&Qg[(size_t)(q0 + g * 16 + fr) * DHn + c * 32 + quad * 8];
            bf16x8 sc;
#pragma unroll
            for (int j = 0; j < 8; ++j)
                sc[j] = (short)f2bf(bf2f((unsigned short)raw[j]) * 0.125f);
            qf[g][c] = sc;
        }
    const f32x4 zero = {0.f, 0.f, 0.f, 0.f};
    f32x4 o[2][4];
    float rs[2] = {0.f, 0.f};
#pragma unroll
    for (int g = 0; g < 2; ++g)
#pragma unroll
        for (int r = 0; r < 4; ++r) o[g][r] = zero;

    const int srow = wv * 8 + (l >> 3);                       // 0..31
    const int lincol = (l & 7) * 8;                           // linear dest chunk
    const int swzcol = (((l & 7) ^ (srow & 7)) << 3);         // swizzled source chunk

    auto stage = [&](int kbase, int bsel) {
        glds16(&Kg[(size_t)(kbase + srow) * DHn + swzcol], &Ks[bsel][srow * 64 + lincol]);
        glds16(&Kg[(size_t)(kbase + srow + 32) * DHn + swzcol], &Ks[bsel][(srow + 32) * 64 + lincol]);
        glds16(&Vg[(size_t)srow * Nn + kbase + swzcol], &VTs[bsel][srow * 64 + lincol]);
        glds16(&Vg[(size_t)(srow + 32) * Nn + kbase + swzcol], &VTs[bsel][(srow + 32) * 64 + lincol]);
        if (t < 16) glds16(&Mg[kbase + t * 4], &Ms[bsel][t * 4]);
    };
    auto compute = [&](int bsel) {
        f32x4 ci[4];
#pragma unroll
        for (int kt = 0; kt < 4; ++kt)
            ci[kt] = *(const f32x4*)&Ms[bsel][kt * 16 + quad * 4];
        bf16x8 kf0[4], kf1[4];
#pragma unroll
        for (int kt = 0; kt < 4; ++kt) {
            int rr = kt * 16 + fr, sw = rr & 7;
            kf0[kt] = *(const bf16x8*)&Ks[bsel][rr * 64 + ((quad ^ sw) << 3)];
            kf1[kt] = *(const bf16x8*)&Ks[bsel][rr * 64 + (((quad + 4) ^ sw) << 3)];
        }
        f32x4 sg[2][4];
#pragma unroll
        for (int g = 0; g < 2; ++g)
#pragma unroll
            for (int kt = 0; kt < 4; ++kt) {
                f32x4 s = __builtin_amdgcn_mfma_f32_16x16x32_bf16(kf0[kt], qf[g][0], ci[kt], 0, 0, 0);
                sg[g][kt] = __builtin_amdgcn_mfma_f32_16x16x32_bf16(kf1[kt], qf[g][1], s, 0, 0, 0);
            }
        bf16x8 vf0[4], vf1[4];
#pragma unroll
        for (int dt = 0; dt < 4; ++dt) {
            int rr = dt * 16 + fr, sw = rr & 7;
            vf0[dt] = *(const bf16x8*)&VTs[bsel][rr * 64 + ((quad ^ sw) << 3)];
            vf1[dt] = *(const bf16x8*)&VTs[bsel][rr * 64 + (((quad + 4) ^ sw) << 3)];
        }
        unsigned short* Pw = Pbuf[wv];
#pragma unroll
        for (int g = 0; g < 2; ++g) {
#pragma unroll
            for (int kt = 0; kt < 4; ++kt) {
                float p0 = __expf(sg[g][kt][0]);
                float p1 = __expf(sg[g][kt][1]);
                float p2 = __expf(sg[g][kt][2]);
                float p3 = __expf(sg[g][kt][3]);
                rs[g] += (p0 + p1) + (p2 + p3);
                uint2 pk;
                pk.x = pack2bf(p0, p1);
                pk.y = pack2bf(p2, p3);
                *(uint2*)&Pw[fr * 72 + kt * 16 + quad * 4] = pk;
            }
            bf16x8 pa0 = *(const bf16x8*)&Pw[fr * 72 + quad * 8];
            bf16x8 pa1 = *(const bf16x8*)&Pw[fr * 72 + 32 + quad * 8];
#pragma unroll
            for (int dt = 0; dt < 4; ++dt) {
                f32x4 t0 = __builtin_amdgcn_mfma_f32_16x16x32_bf16(pa0, vf0[dt], o[g][dt], 0, 0, 0);
                o[g][dt] = __builtin_amdgcn_mfma_f32_16x16x32_bf16(pa1, vf1[dt], t0, 0, 0, 0);
            }
        }
    };

    stage(0, 0);
    __syncthreads();
    for (int r = 0; r < 16; ++r) {
        if (r < 15) stage((r + 1) * 64, (r + 1) & 1);
        compute(r & 1);
        __syncthreads();
    }
#pragma unroll
    for (int g = 0; g < 2; ++g) {
        float r2 = rs[g] + __shfl_xor(rs[g], 16, 64);
        float rfull = r2 + __shfl_xor(r2, 32, 64);   // valid for q = fr on all lanes
        float inv[4];
#pragma unroll
        for (int r = 0; r < 4; ++r) {
            float lv = __shfl(rfull, quad * 4 + r, 64);   // sum for q = quad*4+r
            inv[r] = (lv > 0.f) ? 1.0f / lv : 0.f;
        }
#pragma unroll
        for (int dt = 0; dt < 4; ++dt)
#pragma unroll
            for (int r = 0; r < 4; ++r) {
                int q = q0 + g * 16 + quad * 4 + r;
                attnb[((size_t)(b * Nn + q) * Hh + h) * DHn + dt * 16 + fr] = f2bf(o[g][dt][r] * inv[r]);
            }
    }
}

// ---------------- workspace layout (bytes, all 256-aligned) ----------------
#define OFF_XB     0u            // 8192*768*2   = 12,582,912
#define OFF_WQKVT  12582912u     // 2304*768*2   =  3,538,944
#define OFF_WPROJT 16121856u     // 768*768*2    =  1,179,648
#define OFF_MASKB  17301504u     // 8192*4       =     32,768
#define OFF_QKVB   17334272u     // 3*96*1024*64*2 = 37,748,736 (s=2 unused)
#define OFF_VTB    55083008u     // 96*64*1024*2 = 12,582,912
#define OFF_ATTNB  67665920u     // 8192*768*2   = 12,582,912
// total 80,248,832 bytes

extern "C" void kernel_launch(void* const* d_in, const int* in_sizes, int n_in,
                              void* d_out, int out_size, void* d_ws, size_t ws_size,
                              hipStream_t stream) {
    const float* x      = (const float*)d_in[0];
    const int*   mask   = (const int*)d_in[1];
    const float* w_qkv  = (const float*)d_in[2];
    const float* w_proj = (const float*)d_in[3];
    const float* b_proj = (const float*)d_in[4];
    float* out = (float*)d_out;
    char* ws = (char*)d_ws;
    unsigned short* xb     = (unsigned short*)(ws + OFF_XB);
    unsigned short* wqkvT  = (unsigned short*)(ws + OFF_WQKVT);
    unsigned short* wprojT = (unsigned short*)(ws + OFF_WPROJT);
    float*          maskng = (float*)(ws + OFF_MASKB);
    unsigned short* qkvb   = (unsigned short*)(ws + OFF_QKVB);
    unsigned short* vtb    = (unsigned short*)(ws + OFF_VTB);
    unsigned short* attnb  = (unsigned short*)(ws + OFF_ATTNB);

    // all prep in one launch
    prep_kernel<<<dim3(5376), dim3(256), 0, stream>>>(x, xb, mask, maskng,
                                                      w_qkv, wqkvT, w_proj, wprojT);
    // qkv = x @ w_qkv  (Q/K -> qkvb; V written pre-transposed -> vtb)
    gemm_qkv_kernel<<<dim3(Mrows / 128, N3C / 128), dim3(256), 0, stream>>>(xb, wqkvT, qkvb, vtb);
    // fused masked flash attention: grid (pairs, q-tiles) for XCD L2 locality
    attn_fused<<<dim3(BHn, Nn / 128), dim3(256), 0, stream>>>(qkvb, vtb, maskng, attnb);
    // out = attn @ w_proj + b
    gemm_proj_kernel<<<dim3(Mrows / 128, Ccn / 64), dim3(256), 0, stream>>>(attnb, wprojT, b_proj, out);
}